// Round 2
// baseline (117.706 us; speedup 1.0000x reference)
//
#include <hip/hip_runtime.h>
#include <stdint.h>

// MX fp8_e4m3 fake-quantize, group=32 along last dim (8192x8192 f32).
// 8 elems/lane (2x float4) -> group spans 4 lanes -> quad-only DPP reduction.

typedef float f32x4 __attribute__((ext_vector_type(4)));

// DPP quad_perm max: combine with lane^1 (ctrl 0xB1) and lane^2 (ctrl 0x4E).
template <int CTRL>
__device__ __forceinline__ float dpp_fmax(float x) {
    int y = __builtin_amdgcn_update_dpp(0, __float_as_int(x), CTRL, 0xF, 0xF, true);
    return fmaxf(x, __int_as_float(y));
}

__device__ __forceinline__ float mx_quant_elem(float xx, float inv, float scale) {
    float v  = xx * inv;              // x / scale (exact: scale is a power of two)
    float av = fabsf(v);
    // priv_exp = max(floor(log2(|v|)), -6), bit-exact via exponent field.
    int e = (int)(__float_as_uint(av) >> 23) - 127;   // zero/denorm -> -127
    e = (e < -6) ? -6 : e;
    float sc    = __uint_as_float((uint32_t)(130 - e) << 23);  // 2^(3-e)
    float scinv = __uint_as_float((uint32_t)(124 + e) << 23);  // 2^(e-3)
    float r = floorf(fmaf(av, sc, 0.5f));  // nearest, half away from zero
    r = r * scinv;
    r = fminf(r, 448.0f);                  // saturate e4m3 max-normal
    float q = copysignf(r, v);
    return q * scale;
}

__global__ void __launch_bounds__(256) mxq_kernel(const f32x4* __restrict__ x4,
                                                  f32x4* __restrict__ o4,
                                                  int npairs) {
    int t      = blockIdx.x * blockDim.x + threadIdx.x;
    int stride = gridDim.x * blockDim.x;
    for (int p = t; p < npairs; p += stride) {
        int j = p << 1;
        f32x4 v0 = __builtin_nontemporal_load(&x4[j]);
        f32x4 v1 = __builtin_nontemporal_load(&x4[j + 1]);
        // per-lane absmax of its 8 elements
        float a = fmaxf(fmaxf(fabsf(v0[0]), fabsf(v0[1])),
                        fmaxf(fabsf(v0[2]), fabsf(v0[3])));
        a = fmaxf(a, fmaxf(fmaxf(fabsf(v1[0]), fabsf(v1[1])),
                           fmaxf(fabsf(v1[2]), fabsf(v1[3]))));
        // reduce across the 4 lanes of this 32-elem group (quad-local DPP)
        a = dpp_fmax<0xB1>(a);   // lane ^ 1
        a = dpp_fmax<0x4E>(a);   // lane ^ 2
        // shared scale: se = floor(log2(max)) - 8, clipped; scale = max(2^se, 1e-5)
        int me = (int)(__float_as_uint(a) >> 23);  // biased exponent (a >= 0)
        int se = me - 135;                         // me==0 (zero) -> -135
        float scale = (se < -16) ? 1e-5f
                                 : __uint_as_float((uint32_t)(se + 127) << 23);
        float inv = 1.0f / scale;
        f32x4 r0, r1;
        r0[0] = mx_quant_elem(v0[0], inv, scale);
        r0[1] = mx_quant_elem(v0[1], inv, scale);
        r0[2] = mx_quant_elem(v0[2], inv, scale);
        r0[3] = mx_quant_elem(v0[3], inv, scale);
        r1[0] = mx_quant_elem(v1[0], inv, scale);
        r1[1] = mx_quant_elem(v1[1], inv, scale);
        r1[2] = mx_quant_elem(v1[2], inv, scale);
        r1[3] = mx_quant_elem(v1[3], inv, scale);
        __builtin_nontemporal_store(r0, &o4[j]);
        __builtin_nontemporal_store(r1, &o4[j + 1]);
    }
}

extern "C" void kernel_launch(void* const* d_in, const int* in_sizes, int n_in,
                              void* d_out, int out_size, void* d_ws, size_t ws_size,
                              hipStream_t stream) {
    const f32x4* x4 = (const f32x4*)d_in[0];
    f32x4* o4       = (f32x4*)d_out;
    int n      = in_sizes[0];
    int npairs = n >> 3;                // 8 elems per thread-iteration
    int threads = 256;
    int blocks  = 2048;                 // grid-stride, 8 blocks/CU
    mxq_kernel<<<blocks, threads, 0, stream>>>(x4, o4, npairs);
}

// Round 3
// 111.166 us; speedup vs baseline: 1.0588x; 1.0588x over previous
//
#include <hip/hip_runtime.h>
#include <stdint.h>

// MX fp8_e4m3 fake-quantize, group=32 along last dim (8192x8192 f32).
// 4 elems/lane (coalesced float4), group = 8 lanes; reduction via pure-VALU DPP.

typedef float f32x4 __attribute__((ext_vector_type(4)));

// DPP max combine. CTRL: 0xB1 = quad_perm xor1, 0x4E = quad_perm xor2,
// 0x141 = row_half_mirror (lane ^ 7 within 8-lane half-row).
template <int CTRL>
__device__ __forceinline__ float dpp_fmax(float x) {
    int y = __builtin_amdgcn_update_dpp(0, __float_as_int(x), CTRL, 0xF, 0xF, true);
    return fmaxf(x, __int_as_float(y));
}

__device__ __forceinline__ float group_scale(float a) {
    // a = group absmax (>= 0). se = floor(log2(a)) - 8 via exponent bits;
    // scale = max(2^se, 1e-5); exponent clips fold into the 1e-5 floor.
    int me = (int)(__float_as_uint(a) >> 23);  // biased exponent
    int se = me - 135;                         // zero -> -135
    return (se < -16) ? 1e-5f : __uint_as_float((uint32_t)(se + 127) << 23);
}

__device__ __forceinline__ float mx_quant_elem(float xx, float inv, float scale) {
    float v  = xx * inv;               // x / scale (exact: pow2 scale)
    float av = fabsf(v);
    int e = (int)(__float_as_uint(av) >> 23) - 127;   // zero/denorm -> -127
    e = (e < -6) ? -6 : e;                             // min normal exp
    float sc    = __uint_as_float((uint32_t)(130 - e) << 23);  // 2^(3-e)
    float scinv = __uint_as_float((uint32_t)(124 + e) << 23);  // 2^(e-3)
    float r = floorf(fmaf(av, sc, 0.5f));  // nearest, half away from zero
    r = r * scinv;
    r = fminf(r, 448.0f);                  // saturate e4m3
    return copysignf(r, v) * scale;
}

__device__ __forceinline__ f32x4 process4(f32x4 v) {
    float a = fmaxf(fmaxf(fabsf(v[0]), fabsf(v[1])),
                    fmaxf(fabsf(v[2]), fabsf(v[3])));
    a = dpp_fmax<0xB1>(a);    // xor 1
    a = dpp_fmax<0x4E>(a);    // xor 2
    a = dpp_fmax<0x141>(a);   // xor 7 (half-row mirror) -> max over 8 lanes
    float scale = group_scale(a);
    float inv   = 1.0f / scale;
    f32x4 r;
    r[0] = mx_quant_elem(v[0], inv, scale);
    r[1] = mx_quant_elem(v[1], inv, scale);
    r[2] = mx_quant_elem(v[2], inv, scale);
    r[3] = mx_quant_elem(v[3], inv, scale);
    return r;
}

__global__ void __launch_bounds__(256) mxq_kernel(const f32x4* __restrict__ x4,
                                                  f32x4* __restrict__ o4,
                                                  int nvec4) {
    int t      = blockIdx.x * blockDim.x + threadIdx.x;
    int stride = gridDim.x * blockDim.x;
    // nvec4 = 16,777,216; stride = 524,288 -> exactly 32 iterations, unroll x2.
    for (int i = t; i < nvec4; i += 2 * stride) {
        f32x4 v0 = x4[i];
        f32x4 v1 = x4[i + stride];
        f32x4 r0 = process4(v0);
        f32x4 r1 = process4(v1);
        o4[i]          = r0;
        o4[i + stride] = r1;
    }
}

extern "C" void kernel_launch(void* const* d_in, const int* in_sizes, int n_in,
                              void* d_out, int out_size, void* d_ws, size_t ws_size,
                              hipStream_t stream) {
    const f32x4* x4 = (const f32x4*)d_in[0];
    f32x4* o4       = (f32x4*)d_out;
    int n     = in_sizes[0];
    int nvec4 = n >> 2;
    int threads = 256;
    int blocks  = 2048;   // 8 blocks/CU, grid-stride
    mxq_kernel<<<blocks, threads, 0, stream>>>(x4, o4, nvec4);
}

// Round 4
// 85.025 us; speedup vs baseline: 1.3844x; 1.3075x over previous
//
#include <hip/hip_runtime.h>
#include <stdint.h>

// MX fp8_e4m3 fake-quantize, group=32 along last dim (8192x8192 f32).
// R1 layout (4 elems/lane, fully coalesced float4, 8-lane groups),
// DPP-only reduction, nontemporal stores (keep input L3-resident).

typedef float f32x4 __attribute__((ext_vector_type(4)));

// DPP max combine. CTRL: 0xB1 = quad_perm xor1, 0x4E = quad_perm xor2,
// 0x141 = row_half_mirror (lane ^ 7 within 8-lane half-row).
template <int CTRL>
__device__ __forceinline__ float dpp_fmax(float x) {
    int y = __builtin_amdgcn_update_dpp(0, __float_as_int(x), CTRL, 0xF, 0xF, true);
    return fmaxf(x, __int_as_float(y));
}

__device__ __forceinline__ float group_scale(float a) {
    // a = group absmax (>= 0). se = floor(log2(a)) - 8 via exponent bits;
    // scale = max(2^se, 1e-5); exponent clips fold into the 1e-5 floor.
    int me = (int)(__float_as_uint(a) >> 23);  // biased exponent
    int se = me - 135;                         // zero -> -135
    return (se < -16) ? 1e-5f : __uint_as_float((uint32_t)(se + 127) << 23);
}

__device__ __forceinline__ float mx_quant_elem(float xx, float inv, float scale) {
    float v  = xx * inv;               // x / scale (exact: pow2 scale)
    float av = fabsf(v);
    int e = (int)(__float_as_uint(av) >> 23) - 127;   // zero/denorm -> -127
    e = (e < -6) ? -6 : e;                             // min normal exp
    float sc    = __uint_as_float((uint32_t)(130 - e) << 23);  // 2^(3-e)
    float scinv = __uint_as_float((uint32_t)(124 + e) << 23);  // 2^(e-3)
    float r = floorf(fmaf(av, sc, 0.5f));  // nearest, half away from zero
    r = r * scinv;
    r = fminf(r, 448.0f);                  // saturate e4m3
    return copysignf(r, v) * scale;
}

__device__ __forceinline__ f32x4 process4(f32x4 v) {
    float a = fmaxf(fmaxf(fabsf(v[0]), fabsf(v[1])),
                    fmaxf(fabsf(v[2]), fabsf(v[3])));
    a = dpp_fmax<0xB1>(a);    // xor 1
    a = dpp_fmax<0x4E>(a);    // xor 2
    a = dpp_fmax<0x141>(a);   // xor 7 -> max over the 8-lane group
    float scale = group_scale(a);
    float inv   = 1.0f / scale;
    f32x4 r;
    r[0] = mx_quant_elem(v[0], inv, scale);
    r[1] = mx_quant_elem(v[1], inv, scale);
    r[2] = mx_quant_elem(v[2], inv, scale);
    r[3] = mx_quant_elem(v[3], inv, scale);
    return r;
}

__global__ void __launch_bounds__(256) mxq_kernel(const f32x4* __restrict__ x4,
                                                  f32x4* __restrict__ o4,
                                                  int nvec4) {
    int t      = blockIdx.x * blockDim.x + threadIdx.x;
    int stride = gridDim.x * blockDim.x;
    for (int i = t; i < nvec4; i += stride) {
        f32x4 v = x4[i];                       // cacheable: let L3 keep input
        f32x4 r = process4(v);
        __builtin_nontemporal_store(r, &o4[i]);  // streaming: don't evict input
    }
}

extern "C" void kernel_launch(void* const* d_in, const int* in_sizes, int n_in,
                              void* d_out, int out_size, void* d_ws, size_t ws_size,
                              hipStream_t stream) {
    const f32x4* x4 = (const f32x4*)d_in[0];
    f32x4* o4       = (f32x4*)d_out;
    int n     = in_sizes[0];
    int nvec4 = n >> 2;
    int threads = 256;
    int blocks  = 2048;   // 8 blocks/CU, grid-stride (32 iterations/thread)
    mxq_kernel<<<blocks, threads, 0, stream>>>(x4, o4, nvec4);
}

// Round 5
// 83.670 us; speedup vs baseline: 1.4068x; 1.0162x over previous
//
#include <hip/hip_runtime.h>
#include <stdint.h>

// MX fp8_e4m3 fake-quantize, group=32 along last dim (8192x8192 f32).
// 4 elems/lane coalesced float4, 8-lane groups, DPP-only reduction,
// nontemporal stores (keeps input L3-resident), 4-way ILP unroll.

typedef float f32x4 __attribute__((ext_vector_type(4)));

// DPP max combine. CTRL: 0xB1 = quad_perm xor1, 0x4E = quad_perm xor2,
// 0x141 = row_half_mirror (lane ^ 7 within 8-lane half-row).
template <int CTRL>
__device__ __forceinline__ float dpp_fmax(float x) {
    int y = __builtin_amdgcn_update_dpp(0, __float_as_int(x), CTRL, 0xF, 0xF, true);
    return fmaxf(x, __int_as_float(y));
}

__device__ __forceinline__ float group_scale(float a) {
    // a = group absmax (>= 0). se = floor(log2(a)) - 8 via exponent bits;
    // scale = max(2^se, 1e-5); exponent clips fold into the 1e-5 floor.
    int me = (int)(__float_as_uint(a) >> 23);  // biased exponent
    int se = me - 135;                         // zero -> -135
    return (se < -16) ? 1e-5f : __uint_as_float((uint32_t)(se + 127) << 23);
}

__device__ __forceinline__ float mx_quant_elem(float xx, float inv, float scale) {
    float v  = xx * inv;               // x / scale (exact: pow2 scale)
    float av = fabsf(v);
    int e = (int)(__float_as_uint(av) >> 23) - 127;   // zero/denorm -> -127
    e = (e < -6) ? -6 : e;                             // min normal exp
    float sc    = __uint_as_float((uint32_t)(130 - e) << 23);  // 2^(3-e)
    float scinv = __uint_as_float((uint32_t)(124 + e) << 23);  // 2^(e-3)
    float r = floorf(fmaf(av, sc, 0.5f));  // nearest, half away from zero
    r = r * scinv;
    r = fminf(r, 448.0f);                  // saturate e4m3
    return copysignf(r, v) * scale;
}

__device__ __forceinline__ f32x4 process4(f32x4 v) {
    float a = fmaxf(fmaxf(fabsf(v[0]), fabsf(v[1])),
                    fmaxf(fabsf(v[2]), fabsf(v[3])));
    a = dpp_fmax<0xB1>(a);    // xor 1
    a = dpp_fmax<0x4E>(a);    // xor 2
    a = dpp_fmax<0x141>(a);   // xor 7 -> max over the 8-lane group
    float scale = group_scale(a);
    float inv   = 1.0f / scale;
    f32x4 r;
    r[0] = mx_quant_elem(v[0], inv, scale);
    r[1] = mx_quant_elem(v[1], inv, scale);
    r[2] = mx_quant_elem(v[2], inv, scale);
    r[3] = mx_quant_elem(v[3], inv, scale);
    return r;
}

__global__ void __launch_bounds__(256) mxq_kernel(const f32x4* __restrict__ x4,
                                                  f32x4* __restrict__ o4,
                                                  int nvec4) {
    // Each block trip covers 1024 contiguous vec4s (16 KiB):
    // lane loads at tid + {0,256,512,768} -> 4 coalesced 1KiB/wave loads.
    int tid     = threadIdx.x;
    int base    = blockIdx.x * 1024 + tid;
    int gstride = gridDim.x * 1024;
    for (int i = base; i < nvec4; i += gstride) {
        f32x4 v0 = x4[i];
        f32x4 v1 = x4[i + 256];
        f32x4 v2 = x4[i + 512];
        f32x4 v3 = x4[i + 768];
        f32x4 r0 = process4(v0);
        f32x4 r1 = process4(v1);
        f32x4 r2 = process4(v2);
        f32x4 r3 = process4(v3);
        __builtin_nontemporal_store(r0, &o4[i]);
        __builtin_nontemporal_store(r1, &o4[i + 256]);
        __builtin_nontemporal_store(r2, &o4[i + 512]);
        __builtin_nontemporal_store(r3, &o4[i + 768]);
    }
}

extern "C" void kernel_launch(void* const* d_in, const int* in_sizes, int n_in,
                              void* d_out, int out_size, void* d_ws, size_t ws_size,
                              hipStream_t stream) {
    const f32x4* x4 = (const f32x4*)d_in[0];
    f32x4* o4       = (f32x4*)d_out;
    int n     = in_sizes[0];
    int nvec4 = n >> 2;                 // 16,777,216
    int threads = 256;
    int blocks  = 2048;                 // 8 blocks/CU; 8 trips/thread
    mxq_kernel<<<blocks, threads, 0, stream>>>(x4, o4, nvec4);
}

// Round 6
// 81.231 us; speedup vs baseline: 1.4490x; 1.0300x over previous
//
#include <hip/hip_runtime.h>
#include <stdint.h>

// MX fp8_e4m3 fake-quantize, group=32 along last dim (8192x8192 f32).
// 4 elems/lane coalesced float4, 8-lane groups, DPP-only reduction,
// nontemporal stores (input stays L3-resident). No grid-stride loop:
// each block does exactly one 16 KiB tile -> no store->load loop coupling.

typedef float f32x4 __attribute__((ext_vector_type(4)));

// DPP max combine. CTRL: 0xB1 = quad_perm xor1, 0x4E = quad_perm xor2,
// 0x141 = row_half_mirror (lane ^ 7 within 8-lane half-row).
template <int CTRL>
__device__ __forceinline__ float dpp_fmax(float x) {
    int y = __builtin_amdgcn_update_dpp(0, __float_as_int(x), CTRL, 0xF, 0xF, true);
    return fmaxf(x, __int_as_float(y));
}

__device__ __forceinline__ float group_scale(float a) {
    // a = group absmax (>= 0). se = floor(log2(a)) - 8 via exponent bits;
    // scale = max(2^se, 1e-5); exponent clips fold into the 1e-5 floor.
    int me = (int)(__float_as_uint(a) >> 23);  // biased exponent
    int se = me - 135;                         // zero -> -135
    return (se < -16) ? 1e-5f : __uint_as_float((uint32_t)(se + 127) << 23);
}

__device__ __forceinline__ float mx_quant_elem(float xx, float inv, float scale) {
    float v  = xx * inv;               // x / scale (exact: pow2 scale)
    float av = fabsf(v);
    int e = (int)(__float_as_uint(av) >> 23) - 127;   // zero/denorm -> -127
    e = (e < -6) ? -6 : e;                             // min normal exp
    float sc    = __uint_as_float((uint32_t)(130 - e) << 23);  // 2^(3-e)
    float scinv = __uint_as_float((uint32_t)(124 + e) << 23);  // 2^(e-3)
    float r = floorf(fmaf(av, sc, 0.5f));  // nearest, half away from zero
    r = r * scinv;
    r = fminf(r, 448.0f);                  // saturate e4m3
    return copysignf(r, v) * scale;
}

__device__ __forceinline__ f32x4 process4(f32x4 v) {
    float a = fmaxf(fmaxf(fabsf(v[0]), fabsf(v[1])),
                    fmaxf(fabsf(v[2]), fabsf(v[3])));
    a = dpp_fmax<0xB1>(a);    // xor 1
    a = dpp_fmax<0x4E>(a);    // xor 2
    a = dpp_fmax<0x141>(a);   // xor 7 -> max over the 8-lane group
    float scale = group_scale(a);
    float inv   = 1.0f / scale;
    f32x4 r;
    r[0] = mx_quant_elem(v[0], inv, scale);
    r[1] = mx_quant_elem(v[1], inv, scale);
    r[2] = mx_quant_elem(v[2], inv, scale);
    r[3] = mx_quant_elem(v[3], inv, scale);
    return r;
}

__global__ void __launch_bounds__(256) mxq_kernel(const f32x4* __restrict__ x4,
                                                  f32x4* __restrict__ o4) {
    // One trip per block: 1024 contiguous vec4s (16 KiB), lane at
    // tid + {0,256,512,768} -> 4 fully coalesced 1 KiB/wave loads.
    int i = blockIdx.x * 1024 + threadIdx.x;
    f32x4 v0 = x4[i];
    f32x4 v1 = x4[i + 256];
    f32x4 v2 = x4[i + 512];
    f32x4 v3 = x4[i + 768];
    f32x4 r0 = process4(v0);
    f32x4 r1 = process4(v1);
    f32x4 r2 = process4(v2);
    f32x4 r3 = process4(v3);
    __builtin_nontemporal_store(r0, &o4[i]);
    __builtin_nontemporal_store(r1, &o4[i + 256]);
    __builtin_nontemporal_store(r2, &o4[i + 512]);
    __builtin_nontemporal_store(r3, &o4[i + 768]);
}

extern "C" void kernel_launch(void* const* d_in, const int* in_sizes, int n_in,
                              void* d_out, int out_size, void* d_ws, size_t ws_size,
                              hipStream_t stream) {
    const f32x4* x4 = (const f32x4*)d_in[0];
    f32x4* o4       = (f32x4*)d_out;
    int n      = in_sizes[0];           // 67,108,864 (exactly 16384 * 4096)
    int blocks = n >> 12;               // 4096 elems (1024 vec4) per block
    mxq_kernel<<<blocks, 256, 0, stream>>>(x4, o4);
}